// Round 3
// baseline (85.587 us; speedup 1.0000x reference)
//
#include <hip/hip_runtime.h>
#include <math.h>

#define HH 256
#define WW 256
#define CC 3
#define HW (HH*WW)

__device__ __forceinline__ int reflect(int v, int n) {
    v = (v < 0) ? -v : v;
    v = (v > n - 1) ? (2 * (n - 1) - v) : v;
    return v;
}

// dense index for the 16 distinct r^2 values in a 9x9 window
__device__ __forceinline__ constexpr int r2idx(int r2) {
    switch (r2) {
        case 0:  return 0;  case 1:  return 1;  case 2:  return 2;  case 4:  return 3;
        case 5:  return 4;  case 8:  return 5;  case 9:  return 6;  case 10: return 7;
        case 13: return 8;  case 16: return 9;  case 17: return 10; case 18: return 11;
        case 20: return 12; case 25: return 13; case 26: return 14; default: return 15; // 32
    }
}

// One block (128 threads) per (row y, batch b). Each thread: 2 horizontal
// outputs (x0 = 2*tid, x0+1). No LDS, no barrier. Per window row: 5 float2
// coalesced loads (L1/L2-served) + 18 FMAs. Row reflection is wave-uniform.
__global__ __launch_bounds__(128) void adaptive_log_kernel(
    const float* __restrict__ x, const float* __restrict__ foa,
    float* __restrict__ out)
{
    const int tid = threadIdx.x;
    const int y   = blockIdx.x;      // 0..255
    const int b   = blockIdx.y;      // 0..3
    const int x0  = tid * 2;

    // ---- wave-uniform reflected row offsets (SGPR-resident) ----
    int ryo[9];
    #pragma unroll
    for (int i = 0; i < 9; ++i)
        ryo[i] = reflect(y + i - 4, HH) * WW;

    // ---- weight tables: 1 exp + power chain per output ----
    const float fx = foa[2 * b + 0];
    const float fy = foa[2 * b + 1];

    float w[2][16];
    #pragma unroll
    for (int o = 0; o < 2; ++o) {
        const float ddx = (float)(x0 + o) - fx;
        const float ddy = (float)y - fy;
        const float dist = sqrtf(ddx * ddx + ddy * ddy);
        const float dn = dist * (1.0f / 362.03867196751236f); // 1/sqrt(2*256^2)
        const float sigma = 0.5f + 9.5f * dn;
        const float s2 = sigma * sigma;
        const float inv2s2 = 0.5f / s2;
        const float common = (-1.0f / (float)M_PI) / (s2 * s2) * sqrtf(sigma) * dist;
        const float q   = __expf(-inv2s2);
        const float q2  = q * q;
        const float q4  = q2 * q2;
        const float q5  = q4 * q;
        const float q8  = q4 * q4;
        const float q16 = q8 * q8;
        const float e0 = 1.0f,  e1 = q,        e2 = q2,       e4 = q4;
        const float e5 = q5,    e8 = q8,       e9 = q8 * q,   e10 = q8 * q2;
        const float e13 = q8 * q5,  e16 = q16, e17 = q16 * q, e18 = q16 * q2;
        const float e20 = q16 * q4, e25 = q16 * q8 * q, e26 = q16 * q8 * q2;
        const float e32 = q16 * q16;
        const float ee[16]  = {e0,e1,e2,e4,e5,e8,e9,e10,e13,e16,e17,e18,e20,e25,e26,e32};
        const float r2v[16] = {0,1,2,4,5,8,9,10,13,16,17,18,20,25,26,32};
        const float cb = common * inv2s2;
        #pragma unroll
        for (int k = 0; k < 16; ++k)
            w[o][k] = (common - r2v[k] * cb) * ee[k];
    }

    // ---- 9x9 conv over 3 channels, direct global (cache-served) ----
    const float* xb = x + (size_t)b * (CC * HW);
    const bool edge = (x0 < 4) || (x0 > 250);

    float acc0[CC] = {0.f, 0.f, 0.f};
    float acc1[CC] = {0.f, 0.f, 0.f};

    #pragma unroll
    for (int c = 0; c < CC; ++c) {
        const float* xc = xb + c * HW;
        #pragma unroll
        for (int i = 0; i < 9; ++i) {
            const float* rowp = xc + ryo[i];
            float f[10];
            if (!edge) {
                const float2* rp = (const float2*)(rowp + (x0 - 4));
                const float2 a0 = rp[0];
                const float2 a1 = rp[1];
                const float2 a2 = rp[2];
                const float2 a3 = rp[3];
                const float2 a4 = rp[4];
                f[0]=a0.x; f[1]=a0.y; f[2]=a1.x; f[3]=a1.y; f[4]=a2.x;
                f[5]=a2.y; f[6]=a3.x; f[7]=a3.y; f[8]=a4.x; f[9]=a4.y;
            } else {
                #pragma unroll
                for (int j = 0; j < 10; ++j)
                    f[j] = rowp[reflect(x0 - 4 + j, WW)];
            }
            const int dy2 = (i - 4) * (i - 4);
            float s0 = 0.f, s1 = 0.f;
            #pragma unroll
            for (int m = 0; m < 9; ++m) {
                const int dx2 = (m - 4) * (m - 4);
                s0 += w[0][r2idx(dy2 + dx2)] * f[m];
                s1 += w[1][r2idx(dy2 + dx2)] * f[m + 1];
            }
            acc0[c] += s0;
            acc1[c] += s1;
        }
    }

    // ---- coalesced float2 stores ----
    float* ob = out + (size_t)b * (CC * HW) + y * WW + x0;
    #pragma unroll
    for (int c = 0; c < CC; ++c)
        *(float2*)&ob[c * HW] = make_float2(acc0[c], acc1[c]);
}

extern "C" void kernel_launch(void* const* d_in, const int* in_sizes, int n_in,
                              void* d_out, int out_size, void* d_ws, size_t ws_size,
                              hipStream_t stream) {
    const float* x   = (const float*)d_in[0];   // [4,3,256,256] f32
    const float* foa = (const float*)d_in[1];   // [4,2] f32
    float* out = (float*)d_out;                 // [4,3,256,256] f32

    dim3 grid(HH, 4);    // (row, batch) = 1024 blocks
    dim3 block(128);     // 2 outputs/thread -> one full image row per block
    adaptive_log_kernel<<<grid, block, 0, stream>>>(x, foa, out);
}

// Round 4
// 78.488 us; speedup vs baseline: 1.0904x; 1.0904x over previous
//
#include <hip/hip_runtime.h>
#include <math.h>

#define HH 256
#define WW 256
#define CC 3
#define HW (HH*WW)

#define PW 272              // padded row stride (floats), 16B-aligned rows
#define PH 264              // padded rows per (b,c): rows -4..259
#define PIMG (PH*PW)        // per-channel padded image (floats)

__device__ __forceinline__ int reflect(int v, int n) {
    v = (v < 0) ? -v : v;
    v = (v > n - 1) ? (2 * (n - 1) - v) : v;
    return v;
}

// dense index for the 16 distinct r^2 values in a 9x9 window
__device__ __forceinline__ constexpr int r2idx(int r2) {
    switch (r2) {
        case 0:  return 0;  case 1:  return 1;  case 2:  return 2;  case 4:  return 3;
        case 5:  return 4;  case 8:  return 5;  case 9:  return 6;  case 10: return 7;
        case 13: return 8;  case 16: return 9;  case 17: return 10; case 18: return 11;
        case 20: return 12; case 25: return 13; case 26: return 14; default: return 15; // 32
    }
}

// ---- pre-pad: resolve reflect padding once into ws ----
// pw[(b*3+c)][r][i] = x[b][c][reflect(r-4)][reflect(i-4)], r in 0..263, i in 0..271
__global__ __launch_bounds__(256) void pad_kernel(
    const float* __restrict__ x, float* __restrict__ pw)
{
    const int row = blockIdx.x;          // 0 .. 4*3*264-1
    const int bc  = row / PH;
    const int r   = row - bc * PH;
    const int gr  = reflect(r - 4, HH);
    const float* src = x + (size_t)bc * HW + gr * WW;
    float* dst = pw + (size_t)row * PW;
    for (int i = threadIdx.x; i < PW; i += 256) {
        int gc = i - 4;
        gc = (gc < 0) ? -gc : gc;
        gc = (gc > WW - 1) ? (2 * (WW - 1) - gc) : gc;
        dst[i] = src[gc];
    }
}

// ---- main: branch-free, 4-wide outputs per thread, 3 channels ----
// 128 threads: lane 0..63 -> x0 = 4*lane (full 256-col row per wave),
// tid>>6 -> row within block pair. Grid (128, 4).
__global__ __launch_bounds__(128) void adaptive_log_kernel(
    const float* __restrict__ pin, const float* __restrict__ foa,
    float* __restrict__ out)
{
    const int tid  = threadIdx.x;
    const int lane = tid & 63;
    const int x0   = lane * 4;
    const int y    = blockIdx.x * 2 + (tid >> 6);
    const int b    = blockIdx.y;

    // ---- weight tables for the 4 output pixels ----
    const float fx = foa[2 * b + 0];
    const float fy = foa[2 * b + 1];
    float w[4][16];
    #pragma unroll
    for (int o = 0; o < 4; ++o) {
        const float ddx = (float)(x0 + o) - fx;
        const float ddy = (float)y - fy;
        const float dist = sqrtf(ddx * ddx + ddy * ddy);
        const float dn = dist * (1.0f / 362.03867196751236f); // 1/sqrt(2*256^2)
        const float sigma = 0.5f + 9.5f * dn;
        const float s2 = sigma * sigma;
        const float inv2s2 = 0.5f / s2;
        const float common = (-1.0f / (float)M_PI) / (s2 * s2) * sqrtf(sigma) * dist;
        const float q   = __expf(-inv2s2);
        const float q2  = q * q;
        const float q4  = q2 * q2;
        const float q5  = q4 * q;
        const float q8  = q4 * q4;
        const float q16 = q8 * q8;
        const float ee[16]  = {1.0f, q, q2, q4, q5, q8, q8*q, q8*q2, q8*q5,
                               q16, q16*q, q16*q2, q16*q4, q16*q8*q, q16*q8*q2, q16*q16};
        const float r2v[16] = {0,1,2,4,5,8,9,10,13,16,17,18,20,25,26,32};
        const float cb = common * inv2s2;
        #pragma unroll
        for (int k = 0; k < 16; ++k)
            w[o][k] = (common - r2v[k] * cb) * ee[k];
    }

    // ---- 9x9 conv, 3 channels, all loads aligned float4 from padded ws ----
    float acc[CC][4] = {};
    const float* basep = pin + (size_t)b * (CC * PIMG) + x0; // col x0-4 -> idx x0
    #pragma unroll
    for (int c = 0; c < CC; ++c) {
        const float* cp = basep + c * PIMG;
        #pragma unroll
        for (int i = 0; i < 9; ++i) {
            const float4* rp = (const float4*)(cp + (y + i) * PW); // row y+i-4 -> idx y+i
            const float4 A = rp[0];
            const float4 B = rp[1];
            const float4 C4 = rp[2];
            const float f[12] = {A.x,A.y,A.z,A.w, B.x,B.y,B.z,B.w, C4.x,C4.y,C4.z,C4.w};
            const int dy2 = (i - 4) * (i - 4);
            #pragma unroll
            for (int o = 0; o < 4; ++o) {
                float s = 0.f;
                #pragma unroll
                for (int m = 0; m < 9; ++m)
                    s += w[o][r2idx(dy2 + (m - 4) * (m - 4))] * f[o + m];
                acc[c][o] += s;
            }
        }
    }

    // ---- coalesced float4 stores ----
    float* ob = out + (size_t)b * (CC * HW) + y * WW + x0;
    #pragma unroll
    for (int c = 0; c < CC; ++c)
        *(float4*)&ob[c * HW] = make_float4(acc[c][0], acc[c][1], acc[c][2], acc[c][3]);
}

extern "C" void kernel_launch(void* const* d_in, const int* in_sizes, int n_in,
                              void* d_out, int out_size, void* d_ws, size_t ws_size,
                              hipStream_t stream) {
    const float* x   = (const float*)d_in[0];   // [4,3,256,256] f32
    const float* foa = (const float*)d_in[1];   // [4,2] f32
    float* out = (float*)d_out;                 // [4,3,256,256] f32
    float* pw  = (float*)d_ws;                  // padded input: 4*3*264*272 floats (~3.45 MB)

    // 1) resolve reflect padding into ws (branch-free main kernel follows)
    pad_kernel<<<dim3(4 * CC * PH), dim3(256), 0, stream>>>(x, pw);

    // 2) branch-free adaptive LoG conv
    adaptive_log_kernel<<<dim3(HH / 2, 4), dim3(128), 0, stream>>>(pw, foa, out);
}